// Round 8
// baseline (108.140 us; speedup 1.0000x reference)
//
#include <hip/hip_runtime.h>
#include <math.h>

#define NB   2
#define CIN  128
#define CH   64
#define NPOS 4096

typedef __attribute__((ext_vector_type(8))) short s16x8;   // 8 bf16 (4 VGPRs)
typedef __attribute__((ext_vector_type(4))) float f32x4;

__device__ __forceinline__ unsigned int bfrne(float f) {
    unsigned int u = __float_as_uint(f);
    return (u + 0x7FFFu + ((u >> 16) & 1u)) >> 16;
}
__device__ __forceinline__ unsigned int pk_rne(float lo, float hi) {
    return bfrne(lo) | (bfrne(hi) << 16);
}
// fast half-up pack for non-negative values (exp outputs)
__device__ __forceinline__ unsigned int pk_fast(float lo, float hi) {
    unsigned int a = (__float_as_uint(lo) + 0x8000u) >> 16;
    unsigned int b = (__float_as_uint(hi) + 0x8000u) & 0xFFFF0000u;
    return a | b;
}
__device__ __forceinline__ float bf2f(unsigned short h) {
    return __uint_as_float(((unsigned int)h) << 16);
}

// ---------------------------------------------------------------------------
// Kernel 1: q/k/v projections via MFMA.  16-pos tiles -> 512 blocks (2/CU).
// x staged+transposed in LDS; B = x split hi+lo bf16 (fp32-x accuracy);
// A = W packed bf16 in-register from fp32 (L2-hot, no packw kernel).
// Each wave: 3 of 12 o-tiles.  kT,qT: (b,pos,c) bf16; vbs: (b,c,pos) bf16.
// ---------------------------------------------------------------------------
#define XTS 132
__global__ __launch_bounds__(256) void qkv_kernel(
    const float* __restrict__ x,
    const float* __restrict__ Wq, const float* __restrict__ Wk,
    const float* __restrict__ Wv,
    unsigned short* __restrict__ kT, unsigned short* __restrict__ qT,
    unsigned short* __restrict__ vbs)
{
    __shared__ __align__(16) float xT[16 * XTS];   // 8.25 KB
    const int b  = blockIdx.y;
    const int p0 = blockIdx.x * 16;
    const int tid = threadIdx.x;

    #pragma unroll
    for (int it = 0; it < 2; ++it) {
        int idx = it * 256 + tid;                  // 0..511
        int c = idx >> 2, p4 = (idx & 3) * 4;
        float4 g = *(const float4*)&x[((size_t)b * CIN + c) * NPOS + p0 + p4];
        xT[(p4 + 0) * XTS + c] = g.x;
        xT[(p4 + 1) * XTS + c] = g.y;
        xT[(p4 + 2) * XTS + c] = g.z;
        xT[(p4 + 3) * XTS + c] = g.w;
    }
    __syncthreads();

    const int w = tid >> 6, l = tid & 63, lm = l & 15, lq = l >> 4;
    const int p = p0 + lm;

    s16x8 Bhi[4], Blo[4];
    #pragma unroll
    for (int ck = 0; ck < 4; ++ck) {
        const float* xr = &xT[lm * XTS + ck * 32 + lq * 8];
        union { unsigned int u[4]; s16x8 v; } chv, clv;
        #pragma unroll
        for (int j = 0; j < 4; ++j) {
            float x0 = xr[2 * j], x1 = xr[2 * j + 1];
            unsigned int h0 = bfrne(x0), h1 = bfrne(x1);
            chv.u[j] = h0 | (h1 << 16);
            clv.u[j] = pk_rne(x0 - __uint_as_float(h0 << 16),
                              x1 - __uint_as_float(h1 << 16));
        }
        Bhi[ck] = chv.v; Blo[ck] = clv.v;
    }

    #pragma unroll
    for (int t3 = 0; t3 < 3; ++t3) {
        const int tile = w * 3 + t3;
        const int mat = tile >> 2, o0 = (tile & 3) * 16;
        const float* __restrict__ W = (mat == 0) ? Wq : (mat == 1) ? Wk : Wv;
        f32x4 acc = {0.f, 0.f, 0.f, 0.f};
        #pragma unroll
        for (int ck = 0; ck < 4; ++ck) {
            const float* wp = W + (o0 + lm) * CIN + ck * 32 + lq * 8;
            union { unsigned int u[4]; s16x8 v; } ca;
            #pragma unroll
            for (int j = 0; j < 4; ++j) ca.u[j] = pk_rne(wp[2*j], wp[2*j+1]);
            acc = __builtin_amdgcn_mfma_f32_16x16x32_bf16(ca.v, Bhi[ck], acc, 0,0,0);
            acc = __builtin_amdgcn_mfma_f32_16x16x32_bf16(ca.v, Blo[ck], acc, 0,0,0);
        }
        if (mat < 2) {
            unsigned short* dst = (mat == 0) ? qT : kT;
            uint2 st = make_uint2(pk_rne(acc[0], acc[1]), pk_rne(acc[2], acc[3]));
            *(uint2*)&dst[((size_t)b * NPOS + p) * CH + o0 + lq * 4] = st;
        } else {
            #pragma unroll
            for (int r = 0; r < 4; ++r)
                vbs[((size_t)b * CH + o0 + lq * 4 + r) * NPOS + p] =
                    (unsigned short)bfrne(acc[r]);
        }
    }
}

// ---------------------------------------------------------------------------
// Kernel 2: softmax denominator partials over j-EIGHTHS.  Grid (32 i-tiles,
// 8 jq, b) = 512 blocks (2/CU).  Wave w owns 32 i (a[2][2] reg-resident ->
// each q-tile read feeds 16 MFMAs; no cross-wave reduce).  q staged per
// 64-j tile in frag-ordered LDS, double-buffered -> 1 barrier/iter, 8 iters.
// ---------------------------------------------------------------------------
__global__ __launch_bounds__(256, 4) void stats_kernel(
    const unsigned short* __restrict__ kT,
    const unsigned short* __restrict__ qT,
    float* __restrict__ lpart)
{
    __shared__ __align__(16) unsigned short qbuf[2][4096];   // 16 KB
    const int b  = blockIdx.z;
    const int jq = blockIdx.y;
    const int i0 = blockIdx.x * 128;
    const int tid = threadIdx.x;
    const int w = tid >> 6, l = tid & 63, lm = l & 15, lq = l >> 4;

    s16x8 a[2][2];
    #pragma unroll
    for (int s = 0; s < 2; ++s)
        #pragma unroll
        for (int kc = 0; kc < 2; ++kc)
            a[s][kc] = *(const s16x8*)&kT[
                ((size_t)b * NPOS + i0 + w * 32 + s * 16 + lm) * CH + kc * 32 + lq * 8];

    const unsigned short* qpt =
        qT + ((size_t)b * NPOS + jq * 512 + w * 16 + lm) * CH + lq * 8;
    s16x8 st0 = *(const s16x8*)(qpt);
    s16x8 st1 = *(const s16x8*)(qpt + 32);

    float rs[2][4] = {};
    for (int t = 0; t < 8; ++t) {
        const int buf = t & 1;
        *(s16x8*)&qbuf[buf][(2 * w + 0) * 512 + l * 8] = st0;
        *(s16x8*)&qbuf[buf][(2 * w + 1) * 512 + l * 8] = st1;
        if (t < 7) {
            const unsigned short* qn = qpt + (size_t)(t + 1) * 64 * CH;
            st0 = *(const s16x8*)(qn);
            st1 = *(const s16x8*)(qn + 32);
        }
        __syncthreads();
        #pragma unroll
        for (int js = 0; js < 4; ++js) {
            s16x8 b0 = *(const s16x8*)&qbuf[buf][(js * 2 + 0) * 512 + l * 8];
            s16x8 b1 = *(const s16x8*)&qbuf[buf][(js * 2 + 1) * 512 + l * 8];
            #pragma unroll
            for (int s = 0; s < 2; ++s) {
                f32x4 sc = {0.f, 0.f, 0.f, 0.f};
                sc = __builtin_amdgcn_mfma_f32_16x16x32_bf16(a[s][0], b0, sc, 0,0,0);
                sc = __builtin_amdgcn_mfma_f32_16x16x32_bf16(a[s][1], b1, sc, 0,0,0);
                rs[s][0] += __expf(sc[0]); rs[s][1] += __expf(sc[1]);
                rs[s][2] += __expf(sc[2]); rs[s][3] += __expf(sc[3]);
            }
        }
    }

    #pragma unroll
    for (int s = 0; s < 2; ++s)
        #pragma unroll
        for (int r = 0; r < 4; ++r) {
            rs[s][r] += __shfl_xor(rs[s][r], 1);
            rs[s][r] += __shfl_xor(rs[s][r], 2);
            rs[s][r] += __shfl_xor(rs[s][r], 4);
            rs[s][r] += __shfl_xor(rs[s][r], 8);
        }
    if (lm == 0) {
        #pragma unroll
        for (int s = 0; s < 2; ++s)
            #pragma unroll
            for (int r = 0; r < 4; ++r)
                lpart[(size_t)jq * NB * NPOS + b * NPOS
                      + i0 + w * 32 + s * 16 + lq * 4 + r] = rs[s][r];
    }
}

// ---------------------------------------------------------------------------
// Kernel 3: aggregation over i-EIGHTHS.  Grid (32 j-tiles, 8 iq, b) = 512
// blocks.  U[iq][b][j][c] bf16 partials.  gl (=1/l) reduced INLINE from
// lpart (per-block 512-i slice).  Wave owns 32 j (q-frags reg-resident,
// 64c x 32j acc).  Per 32-i iter: k/v frag-ordered LDS, double-buffered ->
// 1 barrier/iter, 16 iters.  8 score MFMAs -> exp*rl -> wave-private LDS
// roundtrip transpose (2 ds_write_b64 + 1 ds_read_b128; replaces 8
// bpermutes) -> 8 PV MFMAs.  wts rows padded to 40 u16 (80 B: 16B-aligned
// b128 reads, no 8-way banking).
// ---------------------------------------------------------------------------
__global__ __launch_bounds__(256, 4) void agg_kernel(
    const unsigned short* __restrict__ kT,
    const unsigned short* __restrict__ qT,
    const unsigned short* __restrict__ vbs,
    const float* __restrict__ lpart,
    unsigned short* __restrict__ U)
{
    __shared__ __align__(16) unsigned short kbuf[2][2048];   // 8 KB
    __shared__ __align__(16) unsigned short vbuf[2][2048];   // 8 KB
    __shared__ __align__(16) unsigned short wts[4][16][40];  // 5 KB
    __shared__ __align__(16) float rls[512];                 // 2 KB
    const int b  = blockIdx.z;
    const int iq = blockIdx.y;
    const int j0 = blockIdx.x * 128;
    const int tid = threadIdx.x;
    const int w = tid >> 6, l = tid & 63, lm = l & 15, lq = l >> 4;

    // inline gl: reduce 8 lpart partials for this block's 512-i slice
    {
        const float* lp = lpart + (size_t)b * NPOS + iq * 512 + tid * 2;
        float s0 = 0.f, s1 = 0.f;
        #pragma unroll
        for (int qq = 0; qq < 8; ++qq) {
            float2 lv = *(const float2*)(lp + (size_t)qq * NB * NPOS);
            s0 += lv.x; s1 += lv.y;
        }
        rls[tid * 2 + 0] = 1.0f / s0;
        rls[tid * 2 + 1] = 1.0f / s1;
    }

    s16x8 qb[2][2];
    #pragma unroll
    for (int js = 0; js < 2; ++js)
        #pragma unroll
        for (int kc = 0; kc < 2; ++kc)
            qb[js][kc] = *(const s16x8*)&qT[
                ((size_t)b * NPOS + j0 + w * 32 + js * 16 + lm) * CH + kc * 32 + lq * 8];

    const unsigned short* kpt = kT
        + ((size_t)b * NPOS + iq * 512 + (w >> 1) * 16 + lm) * CH
        + (w & 1) * 32 + lq * 8;
    const unsigned short* vpt = vbs
        + ((size_t)b * CH + w * 16 + lm) * NPOS + iq * 512 + lq * 8;

    f32x4 acc[2][4] = {};
    s16x8 kst = *(const s16x8*)kpt;
    s16x8 vst = *(const s16x8*)vpt;

    for (int t = 0; t < 16; ++t) {
        const int buf = t & 1;
        *(s16x8*)&kbuf[buf][w * 512 + l * 8] = kst;
        *(s16x8*)&vbuf[buf][w * 512 + l * 8] = vst;
        if (t < 15) {
            kst = *(const s16x8*)(kpt + (t + 1) * 32 * CH);
            vst = *(const s16x8*)(vpt + (t + 1) * 32);
        }
        __syncthreads();

        s16x8 kA[2][2], vA[4];
        #pragma unroll
        for (int s = 0; s < 2; ++s)
            #pragma unroll
            for (int kc = 0; kc < 2; ++kc)
                kA[s][kc] = *(const s16x8*)&kbuf[buf][(s * 2 + kc) * 512 + l * 8];
        #pragma unroll
        for (int cs = 0; cs < 4; ++cs)
            vA[cs] = *(const s16x8*)&vbuf[buf][cs * 512 + l * 8];

        f32x4 rl0 = *(const f32x4*)&rls[t * 32 + lq * 4];
        f32x4 rl1 = *(const f32x4*)&rls[t * 32 + 16 + lq * 4];

        #pragma unroll
        for (int js = 0; js < 2; ++js) {
            f32x4 s0 = {0,0,0,0}, s1 = {0,0,0,0};
            s0 = __builtin_amdgcn_mfma_f32_16x16x32_bf16(kA[0][0], qb[js][0], s0, 0,0,0);
            s0 = __builtin_amdgcn_mfma_f32_16x16x32_bf16(kA[0][1], qb[js][1], s0, 0,0,0);
            s1 = __builtin_amdgcn_mfma_f32_16x16x32_bf16(kA[1][0], qb[js][0], s1, 0,0,0);
            s1 = __builtin_amdgcn_mfma_f32_16x16x32_bf16(kA[1][1], qb[js][1], s1, 0,0,0);

            unsigned int P0[2], P1[2];
            P0[0] = pk_fast(__expf(s0[0]) * rl0[0], __expf(s0[1]) * rl0[1]);
            P0[1] = pk_fast(__expf(s0[2]) * rl0[2], __expf(s0[3]) * rl0[3]);
            P1[0] = pk_fast(__expf(s1[0]) * rl1[0], __expf(s1[1]) * rl1[1]);
            P1[1] = pk_fast(__expf(s1[2]) * rl1[2], __expf(s1[3]) * rl1[3]);

            // wave-private C->B transpose via LDS roundtrip (no barrier:
            // producer and consumers are the same wave; lgkmcnt orders it)
            *(uint2*)&wts[w][lm][4 * lq]      = make_uint2(P0[0], P0[1]);
            *(uint2*)&wts[w][lm][16 + 4 * lq] = make_uint2(P1[0], P1[1]);
            s16x8 Bv = *(const s16x8*)&wts[w][lm][8 * lq];

            #pragma unroll
            for (int cs = 0; cs < 4; ++cs)
                acc[js][cs] = __builtin_amdgcn_mfma_f32_16x16x32_bf16(
                    vA[cs], Bv, acc[js][cs], 0,0,0);
        }
    }

    unsigned short* Up = U + ((size_t)iq * NB + b) * NPOS * CH;
    #pragma unroll
    for (int js = 0; js < 2; ++js)
        #pragma unroll
        for (int cs = 0; cs < 4; ++cs) {
            uint2 st = make_uint2(pk_rne(acc[js][cs][0], acc[js][cs][1]),
                                  pk_rne(acc[js][cs][2], acc[js][cs][3]));
            *(uint2*)&Up[(size_t)(j0 + w * 32 + js * 16 + lm) * CH
                         + cs * 16 + lq * 4] = st;
        }
}

// ---------------------------------------------------------------------------
// Kernel 4: post projection + residual.  B = sum of 8 bf16 U partials
// (fp32 accumulate), A = Wpost packed bf16 in-register from fp32,
// epilogue adds x in fp32.  Block = (b, 32-pos); 256 blocks.
// ---------------------------------------------------------------------------
__global__ __launch_bounds__(256) void post_kernel(
    const float* __restrict__ x, const float* __restrict__ Wpost,
    const unsigned short* __restrict__ U, float* __restrict__ out)
{
    const int b  = blockIdx.y;
    const int p0 = blockIdx.x * 32;
    const int tid = threadIdx.x;
    const int w = tid >> 6, l = tid & 63, lm = l & 15, lq = l >> 4;
    const int psub = (w & 1) * 16, ohalf = w >> 1;
    const int p = p0 + psub + lm;
    const size_t PS = (size_t)NB * NPOS * CH;

    const unsigned short* u = U + ((size_t)b * NPOS + p) * CH;
    s16x8 Bf[2];
    #pragma unroll
    for (int ck = 0; ck < 2; ++ck) {
        float sv[8] = {};
        #pragma unroll
        for (int qq = 0; qq < 8; ++qq) {
            union { s16x8 v; unsigned short us[8]; } uu;
            uu.v = *(const s16x8*)(u + (size_t)qq * PS + ck * 32 + lq * 8);
            #pragma unroll
            for (int j = 0; j < 8; ++j) sv[j] += bf2f(uu.us[j]);
        }
        union { unsigned int u[4]; s16x8 v; } cb;
        #pragma unroll
        for (int j = 0; j < 4; ++j) cb.u[j] = pk_rne(sv[2*j], sv[2*j+1]);
        Bf[ck] = cb.v;
    }

    #pragma unroll
    for (int ot = 0; ot < 4; ++ot) {
        const int o0 = (ohalf * 4 + ot) * 16;
        f32x4 acc = {0.f, 0.f, 0.f, 0.f};
        #pragma unroll
        for (int ck = 0; ck < 2; ++ck) {
            const float* wp = Wpost + (o0 + lm) * CH + ck * 32 + lq * 8;
            union { unsigned int u[4]; s16x8 v; } ca;
            #pragma unroll
            for (int j = 0; j < 4; ++j) ca.u[j] = pk_rne(wp[2*j], wp[2*j+1]);
            acc = __builtin_amdgcn_mfma_f32_16x16x32_bf16(ca.v, Bf[ck], acc, 0,0,0);
        }
        #pragma unroll
        for (int r = 0; r < 4; ++r) {
            size_t gi = ((size_t)b * CIN + o0 + lq * 4 + r) * NPOS + p;
            out[gi] = x[gi] + acc[r];
        }
    }
}

extern "C" void kernel_launch(void* const* d_in, const int* in_sizes, int n_in,
                              void* d_out, int out_size, void* d_ws, size_t ws_size,
                              hipStream_t stream) {
    const float* x     = (const float*)d_in[0];
    const float* Wq    = (const float*)d_in[1];
    const float* Wk    = (const float*)d_in[2];
    const float* Wv    = (const float*)d_in[3];
    const float* Wpost = (const float*)d_in[4];
    float* out = (float*)d_out;

    // ws: kT(1MB) qT(1MB) vbs(1MB) lpart(256KB) U(8MB bf16, 8 partials)
    unsigned short* kT  = (unsigned short*)d_ws;
    unsigned short* qT  = kT + (size_t)NB * NPOS * CH;
    unsigned short* vbs = qT + (size_t)NB * NPOS * CH;
    float* lpart = (float*)(vbs + (size_t)NB * NPOS * CH);
    unsigned short* U = (unsigned short*)(lpart + (size_t)8 * NB * NPOS);

    qkv_kernel  <<<dim3(NPOS / 16, NB),    256, 0, stream>>>(x, Wq, Wk, Wv, kT, qT, vbs);
    stats_kernel<<<dim3(NPOS / 128, 8, NB), 256, 0, stream>>>(kT, qT, lpart);
    agg_kernel  <<<dim3(NPOS / 128, 8, NB), 256, 0, stream>>>(kT, qT, vbs, lpart, U);
    post_kernel <<<dim3(NPOS / 32, NB),    256, 0, stream>>>(x, Wpost, U, out);
}

// Round 10
// 104.165 us; speedup vs baseline: 1.0382x; 1.0382x over previous
//
#include <hip/hip_runtime.h>
#include <math.h>

#define NB   2
#define CIN  128
#define CH   64
#define NPOS 4096

typedef __attribute__((ext_vector_type(8))) short s16x8;   // 8 bf16 (4 VGPRs)
typedef __attribute__((ext_vector_type(4))) float f32x4;

// frag-block global layouts (shorts):
//  kF/qF: FB(b, pos-tile16, kc) + lane*8 + elem   (1 KB per frag-block)
//  vF   : VB(b, c-tile16, i-tile32) + lane*8 + elem
#define FB(b,T,kc) ((((size_t)(b) * 256 + (size_t)(T)) * 2 + (size_t)(kc)) * 512)
#define VB(b,ct,it) ((((size_t)(b) * 4 + (size_t)(ct)) * 128 + (size_t)(it)) * 512)

__device__ __forceinline__ unsigned int bfrne(float f) {
    unsigned int u = __float_as_uint(f);
    return (u + 0x7FFFu + ((u >> 16) & 1u)) >> 16;
}
__device__ __forceinline__ unsigned int pk_rne(float lo, float hi) {
    return bfrne(lo) | (bfrne(hi) << 16);
}
// fast half-up pack for non-negative values (exp outputs)
__device__ __forceinline__ unsigned int pk_fast(float lo, float hi) {
    unsigned int a = (__float_as_uint(lo) + 0x8000u) >> 16;
    unsigned int b = (__float_as_uint(hi) + 0x8000u) & 0xFFFF0000u;
    return a | b;
}
__device__ __forceinline__ float bf2f(unsigned short h) {
    return __uint_as_float(((unsigned int)h) << 16);
}

// ---------------------------------------------------------------------------
// Kernel 1: q/k/v projections via MFMA, outputs in frag-block layouts.
// 16-pos tiles -> 512 blocks.  x staged+transposed in LDS; B = x split
// hi+lo bf16; A = W packed bf16 in-register from fp32 (L2-hot).
// k/q C-frag -> frag-block: one coalesced uint2/lane.  v: 4 u16 scatter.
// ---------------------------------------------------------------------------
#define XTS 132
__global__ __launch_bounds__(256) void qkv_kernel(
    const float* __restrict__ x,
    const float* __restrict__ Wq, const float* __restrict__ Wk,
    const float* __restrict__ Wv,
    unsigned short* __restrict__ kF, unsigned short* __restrict__ qF,
    unsigned short* __restrict__ vF)
{
    __shared__ __align__(16) float xT[16 * XTS];   // 8.25 KB
    const int b  = blockIdx.y;
    const int pt = blockIdx.x;                     // 16-pos tile index
    const int p0 = pt * 16;
    const int tid = threadIdx.x;

    #pragma unroll
    for (int it = 0; it < 2; ++it) {
        int idx = it * 256 + tid;                  // 0..511
        int c = idx >> 2, p4 = (idx & 3) * 4;
        float4 g = *(const float4*)&x[((size_t)b * CIN + c) * NPOS + p0 + p4];
        xT[(p4 + 0) * XTS + c] = g.x;
        xT[(p4 + 1) * XTS + c] = g.y;
        xT[(p4 + 2) * XTS + c] = g.z;
        xT[(p4 + 3) * XTS + c] = g.w;
    }
    __syncthreads();

    const int w = tid >> 6, l = tid & 63, lm = l & 15, lq = l >> 4;

    s16x8 Bhi[4], Blo[4];
    #pragma unroll
    for (int ck = 0; ck < 4; ++ck) {
        const float* xr = &xT[lm * XTS + ck * 32 + lq * 8];
        union { unsigned int u[4]; s16x8 v; } chv, clv;
        #pragma unroll
        for (int j = 0; j < 4; ++j) {
            float x0 = xr[2 * j], x1 = xr[2 * j + 1];
            unsigned int h0 = bfrne(x0), h1 = bfrne(x1);
            chv.u[j] = h0 | (h1 << 16);
            clv.u[j] = pk_rne(x0 - __uint_as_float(h0 << 16),
                              x1 - __uint_as_float(h1 << 16));
        }
        Bhi[ck] = chv.v; Blo[ck] = clv.v;
    }

    #pragma unroll
    for (int t3 = 0; t3 < 3; ++t3) {
        const int tile = w * 3 + t3;
        const int mat = tile >> 2, o0 = (tile & 3) * 16;
        const float* __restrict__ W = (mat == 0) ? Wq : (mat == 1) ? Wk : Wv;
        f32x4 acc = {0.f, 0.f, 0.f, 0.f};
        #pragma unroll
        for (int ck = 0; ck < 4; ++ck) {
            const float* wp = W + (o0 + lm) * CIN + ck * 32 + lq * 8;
            union { unsigned int u[4]; s16x8 v; } ca;
            #pragma unroll
            for (int j = 0; j < 4; ++j) ca.u[j] = pk_rne(wp[2*j], wp[2*j+1]);
            acc = __builtin_amdgcn_mfma_f32_16x16x32_bf16(ca.v, Bhi[ck], acc, 0,0,0);
            acc = __builtin_amdgcn_mfma_f32_16x16x32_bf16(ca.v, Blo[ck], acc, 0,0,0);
        }
        // C-frag: value at (c = o0 + 4*lq + r, p = p0 + lm)
        if (mat < 2) {
            unsigned short* dst = (mat == 0) ? qF : kF;
            const int kc = o0 >> 5;
            const int lane2 = lm + 16 * (((o0 & 31) >> 3) + (lq >> 1));
            uint2 st = make_uint2(pk_rne(acc[0], acc[1]), pk_rne(acc[2], acc[3]));
            *(uint2*)&dst[FB(b, pt, kc) + lane2 * 8 + (lq & 1) * 4] = st;
        } else {
            const int ct = o0 >> 4;
            const int itile = pt >> 1;
            const int lanebase = 16 * ((pt & 1) * 2 + (lm >> 3));
            #pragma unroll
            for (int r = 0; r < 4; ++r)
                vF[VB(b, ct, itile) + (size_t)(4 * lq + r + lanebase) * 8
                   + (lm & 7)] = (unsigned short)bfrne(acc[r]);
        }
    }
}

// ---------------------------------------------------------------------------
// Kernel 2: softmax denominator partials over j-EIGHTHS.  Grid (32, 8, b)
// = 512 blocks.  Each WAVE independently owns one 32-i tile (it = bx*4+w,
// 0..127) and sweeps its 512-j slice: NO LDS, NO barriers — every fragment
// is one coalesced b128 load from kF/qF.  Prefetched 1 ahead.
// ---------------------------------------------------------------------------
__global__ __launch_bounds__(256, 4) void stats_kernel(
    const unsigned short* __restrict__ kF,
    const unsigned short* __restrict__ qF,
    float* __restrict__ lpart)
{
    const int b  = blockIdx.z;
    const int jq = blockIdx.y;
    const int tid = threadIdx.x;
    const int w = tid >> 6, l = tid & 63, lm = l & 15, lq = l >> 4;
    const int it = blockIdx.x * 4 + w;             // 32-i tile, 0..127

    s16x8 a[2][2];
    #pragma unroll
    for (int s = 0; s < 2; ++s)
        #pragma unroll
        for (int kc = 0; kc < 2; ++kc)
            a[s][kc] = *(const s16x8*)&kF[FB(b, it * 2 + s, kc) + l * 8];

    const unsigned short* q0 = qF + FB(b, jq * 32, 0);   // 32 j-tiles, 1 KB each kc
    s16x8 nb0 = *(const s16x8*)&q0[l * 8];
    s16x8 nb1 = *(const s16x8*)&q0[512 + l * 8];

    float rs[2][4] = {};
    for (int t = 0; t < 32; ++t) {
        s16x8 b0 = nb0, b1 = nb1;
        if (t < 31) {
            nb0 = *(const s16x8*)&q0[(size_t)(t + 1) * 1024 + l * 8];
            nb1 = *(const s16x8*)&q0[(size_t)(t + 1) * 1024 + 512 + l * 8];
        }
        #pragma unroll
        for (int s = 0; s < 2; ++s) {
            f32x4 sc = {0.f, 0.f, 0.f, 0.f};
            sc = __builtin_amdgcn_mfma_f32_16x16x32_bf16(a[s][0], b0, sc, 0,0,0);
            sc = __builtin_amdgcn_mfma_f32_16x16x32_bf16(a[s][1], b1, sc, 0,0,0);
            rs[s][0] += __expf(sc[0]); rs[s][1] += __expf(sc[1]);
            rs[s][2] += __expf(sc[2]); rs[s][3] += __expf(sc[3]);
        }
    }

    #pragma unroll
    for (int s = 0; s < 2; ++s)
        #pragma unroll
        for (int r = 0; r < 4; ++r) {
            rs[s][r] += __shfl_xor(rs[s][r], 1);
            rs[s][r] += __shfl_xor(rs[s][r], 2);
            rs[s][r] += __shfl_xor(rs[s][r], 4);
            rs[s][r] += __shfl_xor(rs[s][r], 8);
        }
    if (lm == 0) {
        #pragma unroll
        for (int s = 0; s < 2; ++s)
            #pragma unroll
            for (int r = 0; r < 4; ++r)
                lpart[(size_t)jq * NB * NPOS + b * NPOS
                      + it * 32 + s * 16 + lq * 4 + r] = rs[s][r];
    }
}

// ---------------------------------------------------------------------------
// Kernel 3: aggregation over i-EIGHTHS.  Grid (32, 8, b) = 512 blocks.
// U[iq][b][j][c] bf16 partials.  gl reduced inline from lpart into rls
// (one barrier, then barrier-FREE main loop).  Wave owns 32 j (q-frags
// reg-resident, 64c x 32j acc); per 32-i iter: k (4 b128) + v (4 b128)
// fragments loaded DIRECTLY from frag-block global layout (coalesced,
// prefetched 1 ahead) — no staging LDS.  8 score MFMAs -> exp*rl ->
// wave-private LDS roundtrip transpose -> 8 PV MFMAs.
// ---------------------------------------------------------------------------
__global__ __launch_bounds__(256, 3) void agg_kernel(
    const unsigned short* __restrict__ kF,
    const unsigned short* __restrict__ qF,
    const unsigned short* __restrict__ vF,
    const float* __restrict__ lpart,
    unsigned short* __restrict__ U)
{
    __shared__ __align__(16) unsigned short wts[4][16][40];  // 5 KB
    __shared__ __align__(16) float rls[512];                 // 2 KB
    const int b  = blockIdx.z;
    const int iq = blockIdx.y;
    const int j0 = blockIdx.x * 128;
    const int tid = threadIdx.x;
    const int w = tid >> 6, l = tid & 63, lm = l & 15, lq = l >> 4;

    // inline gl: reduce 8 lpart partials for this block's 512-i slice
    {
        const float* lp = lpart + (size_t)b * NPOS + iq * 512 + tid * 2;
        float s0 = 0.f, s1 = 0.f;
        #pragma unroll
        for (int qq = 0; qq < 8; ++qq) {
            float2 lv = *(const float2*)(lp + (size_t)qq * NB * NPOS);
            s0 += lv.x; s1 += lv.y;
        }
        rls[tid * 2 + 0] = 1.0f / s0;
        rls[tid * 2 + 1] = 1.0f / s1;
    }

    s16x8 qb[2][2];
    #pragma unroll
    for (int js = 0; js < 2; ++js)
        #pragma unroll
        for (int kc = 0; kc < 2; ++kc)
            qb[js][kc] = *(const s16x8*)&qF[
                FB(b, blockIdx.x * 8 + w * 2 + js, kc) + l * 8];

    f32x4 acc[2][4] = {};
    s16x8 nk[2][2], nv[4];
    #pragma unroll
    for (int s = 0; s < 2; ++s)
        #pragma unroll
        for (int kc = 0; kc < 2; ++kc)
            nk[s][kc] = *(const s16x8*)&kF[FB(b, iq * 32 + s, kc) + l * 8];
    #pragma unroll
    for (int cs = 0; cs < 4; ++cs)
        nv[cs] = *(const s16x8*)&vF[VB(b, cs, iq * 16) + l * 8];

    __syncthreads();   // rls ready (only barrier)

    for (int t = 0; t < 16; ++t) {
        s16x8 kA[2][2] = {{nk[0][0], nk[0][1]}, {nk[1][0], nk[1][1]}};
        s16x8 vA[4] = {nv[0], nv[1], nv[2], nv[3]};
        if (t < 15) {
            #pragma unroll
            for (int s = 0; s < 2; ++s)
                #pragma unroll
                for (int kc = 0; kc < 2; ++kc)
                    nk[s][kc] = *(const s16x8*)&kF[
                        FB(b, iq * 32 + (t + 1) * 2 + s, kc) + l * 8];
            #pragma unroll
            for (int cs = 0; cs < 4; ++cs)
                nv[cs] = *(const s16x8*)&vF[VB(b, cs, iq * 16 + t + 1) + l * 8];
        }

        f32x4 rl0 = *(const f32x4*)&rls[t * 32 + lq * 4];
        f32x4 rl1 = *(const f32x4*)&rls[t * 32 + 16 + lq * 4];

        #pragma unroll
        for (int js = 0; js < 2; ++js) {
            f32x4 s0 = {0,0,0,0}, s1 = {0,0,0,0};
            s0 = __builtin_amdgcn_mfma_f32_16x16x32_bf16(kA[0][0], qb[js][0], s0, 0,0,0);
            s0 = __builtin_amdgcn_mfma_f32_16x16x32_bf16(kA[0][1], qb[js][1], s0, 0,0,0);
            s1 = __builtin_amdgcn_mfma_f32_16x16x32_bf16(kA[1][0], qb[js][0], s1, 0,0,0);
            s1 = __builtin_amdgcn_mfma_f32_16x16x32_bf16(kA[1][1], qb[js][1], s1, 0,0,0);

            unsigned int P0[2], P1[2];
            P0[0] = pk_fast(__expf(s0[0]) * rl0[0], __expf(s0[1]) * rl0[1]);
            P0[1] = pk_fast(__expf(s0[2]) * rl0[2], __expf(s0[3]) * rl0[3]);
            P1[0] = pk_fast(__expf(s1[0]) * rl1[0], __expf(s1[1]) * rl1[1]);
            P1[1] = pk_fast(__expf(s1[2]) * rl1[2], __expf(s1[3]) * rl1[3]);

            // wave-private C->B transpose via LDS roundtrip (no barrier)
            *(uint2*)&wts[w][lm][4 * lq]      = make_uint2(P0[0], P0[1]);
            *(uint2*)&wts[w][lm][16 + 4 * lq] = make_uint2(P1[0], P1[1]);
            s16x8 Bv = *(const s16x8*)&wts[w][lm][8 * lq];

            #pragma unroll
            for (int cs = 0; cs < 4; ++cs)
                acc[js][cs] = __builtin_amdgcn_mfma_f32_16x16x32_bf16(
                    vA[cs], Bv, acc[js][cs], 0,0,0);
        }
    }

    unsigned short* Up = U + ((size_t)iq * NB + b) * NPOS * CH;
    #pragma unroll
    for (int js = 0; js < 2; ++js)
        #pragma unroll
        for (int cs = 0; cs < 4; ++cs) {
            uint2 st = make_uint2(pk_rne(acc[js][cs][0], acc[js][cs][1]),
                                  pk_rne(acc[js][cs][2], acc[js][cs][3]));
            *(uint2*)&Up[(size_t)(j0 + w * 32 + js * 16 + lm) * CH
                         + cs * 16 + lq * 4] = st;
        }
}

// ---------------------------------------------------------------------------
// Kernel 4: post projection + residual.  B = sum of 8 bf16 U partials
// (fp32 accumulate), A = Wpost packed bf16 in-register from fp32,
// epilogue adds x in fp32.  Block = (b, 32-pos); 256 blocks.
// ---------------------------------------------------------------------------
__global__ __launch_bounds__(256) void post_kernel(
    const float* __restrict__ x, const float* __restrict__ Wpost,
    const unsigned short* __restrict__ U, float* __restrict__ out)
{
    const int b  = blockIdx.y;
    const int p0 = blockIdx.x * 32;
    const int tid = threadIdx.x;
    const int w = tid >> 6, l = tid & 63, lm = l & 15, lq = l >> 4;
    const int psub = (w & 1) * 16, ohalf = w >> 1;
    const int p = p0 + psub + lm;
    const size_t PS = (size_t)NB * NPOS * CH;

    const unsigned short* u = U + ((size_t)b * NPOS + p) * CH;
    s16x8 Bf[2];
    #pragma unroll
    for (int ck = 0; ck < 2; ++ck) {
        float sv[8] = {};
        #pragma unroll
        for (int qq = 0; qq < 8; ++qq) {
            union { s16x8 v; unsigned short us[8]; } uu;
            uu.v = *(const s16x8*)(u + (size_t)qq * PS + ck * 32 + lq * 8);
            #pragma unroll
            for (int j = 0; j < 8; ++j) sv[j] += bf2f(uu.us[j]);
        }
        union { unsigned int u[4]; s16x8 v; } cb;
        #pragma unroll
        for (int j = 0; j < 4; ++j) cb.u[j] = pk_rne(sv[2*j], sv[2*j+1]);
        Bf[ck] = cb.v;
    }

    #pragma unroll
    for (int ot = 0; ot < 4; ++ot) {
        const int o0 = (ohalf * 4 + ot) * 16;
        f32x4 acc = {0.f, 0.f, 0.f, 0.f};
        #pragma unroll
        for (int ck = 0; ck < 2; ++ck) {
            const float* wp = Wpost + (o0 + lm) * CH + ck * 32 + lq * 8;
            union { unsigned int u[4]; s16x8 v; } ca;
            #pragma unroll
            for (int j = 0; j < 4; ++j) ca.u[j] = pk_rne(wp[2*j], wp[2*j+1]);
            acc = __builtin_amdgcn_mfma_f32_16x16x32_bf16(ca.v, Bf[ck], acc, 0,0,0);
        }
        #pragma unroll
        for (int r = 0; r < 4; ++r) {
            size_t gi = ((size_t)b * CIN + o0 + lq * 4 + r) * NPOS + p;
            out[gi] = x[gi] + acc[r];
        }
    }
}

extern "C" void kernel_launch(void* const* d_in, const int* in_sizes, int n_in,
                              void* d_out, int out_size, void* d_ws, size_t ws_size,
                              hipStream_t stream) {
    const float* x     = (const float*)d_in[0];
    const float* Wq    = (const float*)d_in[1];
    const float* Wk    = (const float*)d_in[2];
    const float* Wv    = (const float*)d_in[3];
    const float* Wpost = (const float*)d_in[4];
    float* out = (float*)d_out;

    // ws: kF(1MB) qF(1MB) vF(1MB) lpart(256KB) U(8MB bf16, 8 partials)
    unsigned short* kF = (unsigned short*)d_ws;
    unsigned short* qF = kF + (size_t)NB * NPOS * CH;
    unsigned short* vF = qF + (size_t)NB * NPOS * CH;
    float* lpart = (float*)(vF + (size_t)NB * NPOS * CH);
    unsigned short* U = (unsigned short*)(lpart + (size_t)8 * NB * NPOS);

    qkv_kernel  <<<dim3(NPOS / 16, NB),     256, 0, stream>>>(x, Wq, Wk, Wv, kF, qF, vF);
    stats_kernel<<<dim3(32, 8, NB),         256, 0, stream>>>(kF, qF, lpart);
    agg_kernel  <<<dim3(NPOS / 128, 8, NB), 256, 0, stream>>>(kF, qF, vF, lpart, U);
    post_kernel <<<dim3(NPOS / 32, NB),     256, 0, stream>>>(x, Wpost, U, out);
}